// Round 7
// baseline (225.778 us; speedup 1.0000x reference)
//
#include <hip/hip_runtime.h>

#define DIM 128
#define NOUT 40
#define ECAP 1152   // LDS edge-list capacity per 64-node block (mean 384)

typedef __attribute__((ext_vector_type(8))) short bf16x8_t;
typedef __attribute__((ext_vector_type(4))) float f32x4_t;
typedef __attribute__((ext_vector_type(4))) unsigned u32x4_t;

__device__ __forceinline__ ushort f2bf(float f) {
    unsigned u = __float_as_uint(f);
    u += 0x7fffu + ((u >> 16) & 1u);          // round-to-nearest-even
    return (ushort)(u >> 16);
}

// ============ CSR build ============

__global__ __launch_bounds__(256) void hist_kernel(
    const int* __restrict__ dst, int* __restrict__ deg, int n_edges)
{
    int e = blockIdx.x * 256 + threadIdx.x;
    if (e < n_edges) atomicAdd(&deg[dst[e]], 1);
}

__global__ __launch_bounds__(256) void reduce_kernel(
    const int* __restrict__ deg, int* __restrict__ bsum, int n)
{
    int t = threadIdx.x;
    int base = blockIdx.x * 1024 + t;
    int s = 0;
    #pragma unroll
    for (int i = 0; i < 4; ++i) { int idx = base + i * 256; s += (idx < n) ? deg[idx] : 0; }
    for (int o = 32; o; o >>= 1) s += __shfl_down(s, o, 64);
    __shared__ int l[4];
    if ((t & 63) == 0) l[t >> 6] = s;
    __syncthreads();
    if (t == 0) bsum[blockIdx.x] = l[0] + l[1] + l[2] + l[3];
}

__global__ __launch_bounds__(128) void scan_sums_kernel(
    int* __restrict__ bsum, int nb, int* __restrict__ off_n)
{
    __shared__ int l[128];
    int t = threadIdx.x;
    int c = (nb + 127) >> 7;
    int b = t * c, e = min(b + c, nb);
    int s = 0;
    for (int i = b; i < e; ++i) s += bsum[i];
    l[t] = s;
    __syncthreads();
    for (int d = 1; d < 128; d <<= 1) {
        int u = (t >= d) ? l[t - d] : 0;
        __syncthreads();
        l[t] += u;
        __syncthreads();
    }
    int pre = l[t] - s;
    for (int i = b; i < e; ++i) { int v = bsum[i]; bsum[i] = pre; pre += v; }
    if (t == 127) *off_n = l[127];
}

// writes exclusive-scan offsets AND re-zeroes deg (it becomes the fill cursor)
__global__ __launch_bounds__(256) void apply_kernel(
    int* __restrict__ deg, const int* __restrict__ bsum,
    int* __restrict__ off, int n)
{
    int t = threadIdx.x;
    int i0 = blockIdx.x * 1024 + t * 4;
    int d0 = (i0     < n) ? deg[i0]     : 0;
    int d1 = (i0 + 1 < n) ? deg[i0 + 1] : 0;
    int d2 = (i0 + 2 < n) ? deg[i0 + 2] : 0;
    int d3 = (i0 + 3 < n) ? deg[i0 + 3] : 0;
    int s = d0 + d1 + d2 + d3;
    int inc = s;
    for (int o = 1; o < 64; o <<= 1) {
        int u = __shfl_up(inc, o, 64);
        if ((t & 63) >= o) inc += u;
    }
    __shared__ int wt[4];
    if ((t & 63) == 63) wt[t >> 6] = inc;
    __syncthreads();
    int wpre = 0;
    #pragma unroll
    for (int i = 0; i < 4; ++i) wpre += (i < (t >> 6)) ? wt[i] : 0;
    int excl = bsum[blockIdx.x] + wpre + inc - s;
    if (i0     < n) { off[i0]     = excl;                deg[i0]     = 0; }
    if (i0 + 1 < n) { off[i0 + 1] = excl + d0;           deg[i0 + 1] = 0; }
    if (i0 + 2 < n) { off[i0 + 2] = excl + d0 + d1;      deg[i0 + 2] = 0; }
    if (i0 + 3 < n) { off[i0 + 3] = excl + d0 + d1 + d2; deg[i0 + 3] = 0; }
}

__global__ __launch_bounds__(256) void fill_kernel(
    const int* __restrict__ src, const int* __restrict__ dst,
    const int* __restrict__ off, int* __restrict__ cursor,
    int* __restrict__ csr_src, int n_edges)
{
    int e = blockIdx.x * 256 + threadIdx.x;
    if (e >= n_edges) return;
    int d = dst[e];
    int pos = off[d] + atomicAdd(&cursor[d], 1);
    csr_src[pos] = src[e];
}

// ============ prep: cast x -> bf16  +  pack W/Wh into B-frag order ============
__global__ __launch_bounds__(256) void prep_kernel(
    const float* __restrict__ x, ushort* __restrict__ xb, int n4,
    const float* __restrict__ Ws, const float* __restrict__ Wh,
    ushort* __restrict__ pW, ushort* __restrict__ pWh)
{
    int i = blockIdx.x * 256 + threadIdx.x;
    if (i < n4) {
        float4 v = reinterpret_cast<const float4*>(x)[i];
        reinterpret_cast<ushort4*>(xb)[i] =
            make_ushort4(f2bf(v.x), f2bf(v.y), f2bf(v.z), f2bf(v.w));
        return;
    }
    int tid = i - n4;
    if (tid < 3 * 16384) {                       // layer weights, NCB=8
        int l = tid / 16384, r = tid % 16384;
        int j = r & 7, lane = (r >> 3) & 63, cb = (r >> 9) & 7, ks = r >> 12;
        int k  = ks * 32 + (lane >> 4) * 8 + j;
        int nn = cb * 16 + (lane & 15);
        pW[tid] = f2bf(Ws[(size_t)l * DIM * DIM + (size_t)k * DIM + nn]);
    } else {
        int r = tid - 3 * 16384;                 // head, NCB=3 (cols padded to 48)
        if (r < 4 * 3 * 64 * 8) {
            int j = r & 7, lane = (r >> 3) & 63;
            int rem = r >> 9;
            int cb = rem % 3, ks = rem / 3;
            int k  = ks * 32 + (lane >> 4) * 8 + j;
            int nn = cb * 16 + (lane & 15);
            pWh[r] = (nn < NOUT) ? f2bf(Wh[(size_t)k * NOUT + nn]) : (ushort)0;
        }
    }
}

// ============ gather helper: accumulate rows idx[kb..ke) into a[4][8] ============
template<typename IP>
__device__ __forceinline__ void gather_rows(
    const ushort* __restrict__ xb, const IP idx,
    int kb, int ke, int kofs, float a[4][8])
{
    int k = kb;
    for (; k + 3 < ke; k += 4) {                 // 16 x 16B loads in flight
        int s0 = idx[k], s1 = idx[k + 1], s2 = idx[k + 2], s3 = idx[k + 3];
        const ushort* r0 = xb + (size_t)s0 * DIM + kofs;
        const ushort* r1 = xb + (size_t)s1 * DIM + kofs;
        const ushort* r2 = xb + (size_t)s2 * DIM + kofs;
        const ushort* r3 = xb + (size_t)s3 * DIM + kofs;
        u32x4_t u0[4], u1[4], u2[4], u3[4];
        #pragma unroll
        for (int s = 0; s < 4; ++s) u0[s] = *reinterpret_cast<const u32x4_t*>(r0 + s * 32);
        #pragma unroll
        for (int s = 0; s < 4; ++s) u1[s] = *reinterpret_cast<const u32x4_t*>(r1 + s * 32);
        #pragma unroll
        for (int s = 0; s < 4; ++s) u2[s] = *reinterpret_cast<const u32x4_t*>(r2 + s * 32);
        #pragma unroll
        for (int s = 0; s < 4; ++s) u3[s] = *reinterpret_cast<const u32x4_t*>(r3 + s * 32);
        #pragma unroll
        for (int s = 0; s < 4; ++s)
            #pragma unroll
            for (int q = 0; q < 4; ++q) {
                a[s][2*q]   += (__uint_as_float(u0[s][q] << 16)
                              + __uint_as_float(u1[s][q] << 16))
                             + (__uint_as_float(u2[s][q] << 16)
                              + __uint_as_float(u3[s][q] << 16));
                a[s][2*q+1] += (__uint_as_float(u0[s][q] & 0xffff0000u)
                              + __uint_as_float(u1[s][q] & 0xffff0000u))
                             + (__uint_as_float(u2[s][q] & 0xffff0000u)
                              + __uint_as_float(u3[s][q] & 0xffff0000u));
            }
    }
    for (; k < ke; ++k) {
        const ushort* r0 = xb + (size_t)idx[k] * DIM + kofs;
        #pragma unroll
        for (int s = 0; s < 4; ++s) {
            u32x4_t v = *reinterpret_cast<const u32x4_t*>(r0 + s * 32);
            #pragma unroll
            for (int q = 0; q < 4; ++q) {
                a[s][2*q]   += __uint_as_float(v[q] << 16);
                a[s][2*q+1] += __uint_as_float(v[q] & 0xffff0000u);
            }
        }
    }
}

// ============ fused layer: gather -> A-frags -> MFMA -> pack-store (HEAD chains head GEMM) ============
template<bool HEAD>
__global__ __launch_bounds__(256) void gin_fused_mfma(
    const ushort* __restrict__ xb,
    const int* __restrict__ csr, const int* __restrict__ off,
    const ushort* __restrict__ pW, const float* __restrict__ bias,
    const ushort* __restrict__ pWh, const float* __restrict__ bh,
    const float* __restrict__ eps, int layer,
    ushort* __restrict__ Y, float* __restrict__ out, int n_nodes)
{
    __shared__ ushort lds[4][16][136];   // C-tile staging
    __shared__ int elist[ECAP];          // block edge list (contiguous CSR range)

    const int t = threadIdx.x, wave = t >> 6, lane = t & 63;
    const int rloc = lane & 15;
    const int kseg = lane >> 4;
    const int kofs = kseg * 8;
    const int blkbase = (int)blockIdx.x * 64;   // signed: min() overload needs int,int
    const int row16 = blkbase + wave * 16;
    const int node  = row16 + rloc;
    const int nclamp = min(node, n_nodes - 1);
    const float e1 = 1.0f + eps[layer];

    // ---- stage block's edge list in LDS (coalesced) ----
    const int blk_lo = off[min(blkbase, n_nodes)];
    const int blk_hi = off[min(blkbase + 64, n_nodes)];
    const int etot = blk_hi - blk_lo;
    const bool use_lds = (etot <= ECAP);
    if (use_lds)
        for (int i = t; i < etot; i += 256) elist[i] = csr[blk_lo + i];
    __syncthreads();

    // ---- self term ----
    float a[4][8];
    {
        const ushort* xr = xb + (size_t)nclamp * DIM + kofs;
        #pragma unroll
        for (int s = 0; s < 4; ++s) {
            u32x4_t v = *reinterpret_cast<const u32x4_t*>(xr + s * 32);
            #pragma unroll
            for (int q = 0; q < 4; ++q) {
                a[s][2*q]   = e1 * __uint_as_float(v[q] << 16);
                a[s][2*q+1] = e1 * __uint_as_float(v[q] & 0xffff0000u);
            }
        }
    }
    // ---- neighbor gather ----
    {
        int kb = off[nclamp] - blk_lo, ke2 = off[nclamp + 1] - blk_lo;
        if (use_lds) gather_rows(xb, (const int*)elist, kb, ke2, kofs, a);
        else         gather_rows(xb, csr + blk_lo,      kb, ke2, kofs, a);
    }

    // ---- to bf16 A-frags ----
    bf16x8_t af[4];
    #pragma unroll
    for (int s = 0; s < 4; ++s)
        #pragma unroll
        for (int j = 0; j < 8; ++j) af[s][j] = (short)f2bf(a[s][j]);

    // ---- layer GEMM ----
    const bf16x8_t* pw8 = reinterpret_cast<const bf16x8_t*>(pW);
    f32x4_t acc[8];
    #pragma unroll
    for (int cb = 0; cb < 8; ++cb) acc[cb] = (f32x4_t)(bias[cb * 16 + rloc]);
    #pragma unroll
    for (int cb = 0; cb < 8; ++cb) {
        const bf16x8_t* bp = pw8 + cb * 64 + lane;
        acc[cb] = __builtin_amdgcn_mfma_f32_16x16x32_bf16(af[0], bp[0],    acc[cb], 0, 0, 0);
        acc[cb] = __builtin_amdgcn_mfma_f32_16x16x32_bf16(af[1], bp[512],  acc[cb], 0, 0, 0);
        acc[cb] = __builtin_amdgcn_mfma_f32_16x16x32_bf16(af[2], bp[1024], acc[cb], 0, 0, 0);
        acc[cb] = __builtin_amdgcn_mfma_f32_16x16x32_bf16(af[3], bp[1536], acc[cb], 0, 0, 0);
    }

    // ---- stage C tile in LDS (C/D: col=lane&15, row=(lane>>4)*4+reg) ----
    #pragma unroll
    for (int cb = 0; cb < 8; ++cb)
        #pragma unroll
        for (int r = 0; r < 4; ++r)
            lds[wave][kseg * 4 + r][cb * 16 + rloc] = f2bf(acc[cb][r]);
    __syncthreads();

    if (!HEAD) {
        #pragma unroll
        for (int p = 0; p < 4; ++p) {
            int rl = p * 4 + kseg;
            int row = row16 + rl;
            bf16x8_t v = *reinterpret_cast<const bf16x8_t*>(&lds[wave][rl][rloc * 8]);
            if (row < n_nodes)
                *reinterpret_cast<bf16x8_t*>(Y + (size_t)row * DIM + rloc * 8) = v;
        }
    } else {
        bf16x8_t hf[4];
        #pragma unroll
        for (int s = 0; s < 4; ++s)
            hf[s] = *reinterpret_cast<const bf16x8_t*>(&lds[wave][rloc][s * 32 + kofs]);
        const bf16x8_t* ph8 = reinterpret_cast<const bf16x8_t*>(pWh);
        f32x4_t hacc[3];
        #pragma unroll
        for (int cb = 0; cb < 3; ++cb) {
            int col = cb * 16 + rloc;
            hacc[cb] = (f32x4_t)((col < NOUT) ? bh[col] : 0.f);
            const bf16x8_t* bp = ph8 + cb * 64 + lane;
            hacc[cb] = __builtin_amdgcn_mfma_f32_16x16x32_bf16(hf[0], bp[0],   hacc[cb], 0, 0, 0);
            hacc[cb] = __builtin_amdgcn_mfma_f32_16x16x32_bf16(hf[1], bp[192], hacc[cb], 0, 0, 0);
            hacc[cb] = __builtin_amdgcn_mfma_f32_16x16x32_bf16(hf[2], bp[384], hacc[cb], 0, 0, 0);
            hacc[cb] = __builtin_amdgcn_mfma_f32_16x16x32_bf16(hf[3], bp[576], hacc[cb], 0, 0, 0);
        }
        #pragma unroll
        for (int cb = 0; cb < 3; ++cb) {
            int col = cb * 16 + rloc;
            if (col < NOUT) {
                #pragma unroll
                for (int r = 0; r < 4; ++r) {
                    int row = row16 + kseg * 4 + r;
                    if (row < n_nodes) out[(size_t)row * NOUT + col] = hacc[cb][r];
                }
            }
        }
    }
}

extern "C" void kernel_launch(void* const* d_in, const int* in_sizes, int n_in,
                              void* d_out, int out_size, void* d_ws, size_t ws_size,
                              hipStream_t stream) {
    (void)n_in; (void)out_size; (void)ws_size;
    const float* x    = (const float*)d_in[0];
    const int*   edge = (const int*)d_in[1];
    const float* eps  = (const float*)d_in[2];
    const float* Ws   = (const float*)d_in[3];
    const float* bs   = (const float*)d_in[4];
    const float* Wh   = (const float*)d_in[5];
    const float* bh   = (const float*)d_in[6];

    const int n_nodes = in_sizes[0] / DIM;
    const int n_edges = in_sizes[1] / 2;
    const int* src = edge;
    const int* dst = edge + n_edges;

    const size_t halfE = (size_t)n_nodes * DIM;
    ushort* buf0 = (ushort*)d_ws;
    ushort* buf1 = buf0 + halfE;
    char* p = (char*)(buf1 + halfE);
    int* deg  = (int*)p;            p += (size_t)n_nodes * 4;
    int* off  = (int*)p;            p += ((size_t)n_nodes + 1) * 4;
    int* bsum = (int*)p;            p += 512;
    int* csr  = (int*)p;            p += (size_t)n_edges * 4;
    p = (char*)(((uintptr_t)p + 15) & ~(uintptr_t)15);
    ushort* pW  = (ushort*)p;       p += 3 * 16384 * 2;
    ushort* pWh = (ushort*)p;

    const dim3 blk(256);
    const int edge_grid  = (n_edges + 255) / 256;
    const int fused_grid = (n_nodes + 63) / 64;
    const int nscan = (n_nodes + 1023) / 1024;
    const int cast_n4 = n_nodes * DIM / 4;
    const int prep_items = cast_n4 + 3 * 16384 + 4 * 3 * 64 * 8;

    // ---- CSR build (once) ----
    (void)hipMemsetAsync(deg, 0, (size_t)n_nodes * sizeof(int), stream);
    hist_kernel<<<edge_grid, blk, 0, stream>>>(dst, deg, n_edges);
    reduce_kernel<<<nscan, blk, 0, stream>>>(deg, bsum, n_nodes);
    scan_sums_kernel<<<1, 128, 0, stream>>>(bsum, nscan, off + n_nodes);
    apply_kernel<<<nscan, blk, 0, stream>>>(deg, bsum, off, n_nodes);   // also zeroes deg
    fill_kernel<<<edge_grid, blk, 0, stream>>>(src, dst, off, deg, csr, n_edges);

    // ---- cast + pack (one kernel) ----
    prep_kernel<<<(prep_items + 255) / 256, blk, 0, stream>>>(
        x, buf0, cast_n4, Ws, Wh, pW, pWh);

    // ---- 3 fused layers; layer 2 chains the head ----
    gin_fused_mfma<false><<<fused_grid, blk, 0, stream>>>(
        buf0, csr, off, pW,          bs,           pWh, bh, eps, 0, buf1, nullptr, n_nodes);
    gin_fused_mfma<false><<<fused_grid, blk, 0, stream>>>(
        buf1, csr, off, pW + 16384,  bs + DIM,     pWh, bh, eps, 1, buf0, nullptr, n_nodes);
    gin_fused_mfma<true><<<fused_grid, blk, 0, stream>>>(
        buf0, csr, off, pW + 32768,  bs + 2 * DIM, pWh, bh, eps, 2, nullptr, (float*)d_out, n_nodes);
}